// Round 5
// baseline (544.036 us; speedup 1.0000x reference)
//
#include <hip/hip_runtime.h>
#include <hip/hip_bf16.h>
#include <stdint.h>

#define N_NODES 8192
#define IN_F    256
#define OUT_F   64
#define NEG_SLOPE 0.2f
#define CAP     1024
#define ROWS_PER_BLOCK 16
#define DET_WORDS  4096   // 16 KB of adjacency scanned per block (L2-cached)
#define DET_HALVES 8192   // 16 KB of X scanned per block

static __device__ __forceinline__ float bf2f(unsigned short u) {
    union { unsigned int i; float f; } v; v.i = ((unsigned int)u) << 16; return v.f;
}
static __device__ __forceinline__ float bflo(unsigned int u) {
    union { unsigned int i; float f; } v; v.i = u << 16; return v.f;
}
static __device__ __forceinline__ float bfhi(unsigned int u) {
    union { unsigned int i; float f; } v; v.i = u & 0xFFFF0000u; return v.f;
}
static __device__ __forceinline__ unsigned short f2bf(float f) {
    union { float f; unsigned int i; } v; v.f = f;
    unsigned int x = v.i;
    unsigned int lsb = (x >> 16) & 1u;
    x += 0x7FFFu + lsb;
    return (unsigned short)(x >> 16);
}

// Per-block adjacency-width detection on the shared 16KB prefix
// (deterministic across blocks; L2-cached). Violation bits: bit0 = not
// 4-byte elems (words in {0,1,0x3F800000}), bit1 = not 2-byte (halves in
// {0,1,0x3F80}), bit2 = not 1-byte (bytes in {0,1}).
// Width = 4 if !bit0 else 2 if !bit1 else 1.
static __device__ __forceinline__ int adj_viol_local(const unsigned int* w, int tid) {
    int viol = 0;
    for (int i = tid; i < DET_WORDS; i += 256) {
        unsigned int v = w[i];
        if (v) {
            if (v != 1u && v != 0x3F800000u) viol |= 1;
            unsigned int h0 = v & 0xFFFFu, h1 = v >> 16;
            if ((h0 != 0u && h0 != 1u && h0 != 0x3F80u) ||
                (h1 != 0u && h1 != 1u && h1 != 0x3F80u)) viol |= 2;
            unsigned int b0 = v & 0xFFu, b1 = (v >> 8) & 0xFFu,
                         b2 = (v >> 16) & 0xFFu, b3 = v >> 24;
            if (b0 > 1u || b1 > 1u || b2 > 1u || b3 > 1u) viol |= 4;
        }
    }
    return viol;
}

// Per-block X dtype detection on X's first 16KB: nonzero => fp32 (u16 halves
// with bf16-exponent >= 133 occur w.p. ~0.48 per fp32 mantissa half, never
// in bf16 N(0,1) data).  R1-R4 evidence: fires fp32 for this harness.
static __device__ __forceinline__ int x_is_f32_local(const unsigned short* x, int tid) {
    int viol = 0;
    for (int i = tid; i < DET_HALVES; i += 256) {
        unsigned int e = ((unsigned int)x[i] >> 7) & 0xFFu;
        if (e >= 133u) viol = 1;
    }
    return viol;
}

static __device__ __forceinline__ void block_or(int v, int tid, int* sdet, int slot) {
    for (int o = 32; o; o >>= 1) v |= __shfl_xor(v, o, 64);
    if ((tid & 63) == 0 && v) atomicOr(&sdet[slot], v);
}

// ---------------------------------------------------------------------------
// proj = X @ W (fp32 accum), s_i = proj @ a[:64], s_j = proj @ a[64:]
// 512 blocks x 16 rows. Thread t: row=t>>4, cols (t&15)*4..+3.
// ---------------------------------------------------------------------------
__global__ __launch_bounds__(256) void proj_kernel(
    const void* __restrict__ Xv, const void* __restrict__ Wv,
    const void* __restrict__ Av,
    float* __restrict__ proj, float* __restrict__ si, float* __restrict__ sj) {
    __shared__ unsigned short wL[IN_F * OUT_F];  // 32 KB
    __shared__ unsigned short xL[16 * IN_F];     // 8 KB
    __shared__ float aL[2 * OUT_F];
    __shared__ int sdet[2];

    int tid = threadIdx.x;
    if (tid == 0) { sdet[0] = 0; sdet[1] = 0; }
    __syncthreads();
    block_or(x_is_f32_local((const unsigned short*)Xv, tid), tid, sdet, 1);
    __syncthreads();
    bool xf32 = (sdet[1] != 0);

    int row0 = blockIdx.x * 16;
    int tc = tid & 15;
    int r  = tid >> 4;
    int c0 = tc * 4;
    int row = row0 + r;

    float acc0 = 0.f, acc1 = 0.f, acc2 = 0.f, acc3 = 0.f;

    if (xf32) {
        const float* Xf = (const float*)Xv;
        const float* Wf = (const float*)Wv;
        const float* Af = (const float*)Av;
        if (tid < 2 * OUT_F) aL[tid] = Af[tid];
        __syncthreads();
        const float4* xr = (const float4*)(Xf + (size_t)row * IN_F);
#pragma unroll 2
        for (int kv = 0; kv < IN_F / 4; ++kv) {
            float4 xq = xr[kv];
#pragma unroll
            for (int t = 0; t < 4; ++t) {
                float x = (t == 0) ? xq.x : (t == 1) ? xq.y : (t == 2) ? xq.z : xq.w;
                float4 wq = *(const float4*)(Wf + (size_t)(kv * 4 + t) * OUT_F + c0);
                acc0 = fmaf(x, wq.x, acc0);
                acc1 = fmaf(x, wq.y, acc1);
                acc2 = fmaf(x, wq.z, acc2);
                acc3 = fmaf(x, wq.w, acc3);
            }
        }
    } else {
        const unsigned short* Xh = (const unsigned short*)Xv;
        const unsigned short* Wh = (const unsigned short*)Wv;
        const unsigned short* Ah = (const unsigned short*)Av;
        for (int i = tid; i < (IN_F * OUT_F) / 8; i += 256)
            ((uint4*)wL)[i] = ((const uint4*)Wh)[i];
        for (int i = tid; i < (16 * IN_F) / 8; i += 256)
            ((uint4*)xL)[i] = ((const uint4*)(Xh + (size_t)row0 * IN_F))[i];
        if (tid < 2 * OUT_F) aL[tid] = bf2f(Ah[tid]);
        __syncthreads();

        const uint4* xrv = (const uint4*)&xL[r * IN_F];
#pragma unroll 4
        for (int kv = 0; kv < IN_F / 8; ++kv) {
            uint4 xq = xrv[kv];
#pragma unroll
            for (int h = 0; h < 4; ++h) {
                unsigned int xp = (h == 0) ? xq.x : (h == 1) ? xq.y : (h == 2) ? xq.z : xq.w;
                int k0 = kv * 8 + h * 2;
                uint2 w0 = *(const uint2*)&wL[(k0 + 0) * OUT_F + c0];
                uint2 w1 = *(const uint2*)&wL[(k0 + 1) * OUT_F + c0];
                float xa = bflo(xp), xb = bfhi(xp);
                acc0 = fmaf(xa, bflo(w0.x), acc0);
                acc1 = fmaf(xa, bfhi(w0.x), acc1);
                acc2 = fmaf(xa, bflo(w0.y), acc2);
                acc3 = fmaf(xa, bfhi(w0.y), acc3);
                acc0 = fmaf(xb, bflo(w1.x), acc0);
                acc1 = fmaf(xb, bfhi(w1.x), acc1);
                acc2 = fmaf(xb, bflo(w1.y), acc2);
                acc3 = fmaf(xb, bfhi(w1.y), acc3);
            }
        }
    }

    *(float4*)&proj[(size_t)row * OUT_F + c0] = make_float4(acc0, acc1, acc2, acc3);

    float sa = acc0 * aL[c0] + acc1 * aL[c0 + 1] + acc2 * aL[c0 + 2] + acc3 * aL[c0 + 3];
    float sb = acc0 * aL[OUT_F + c0] + acc1 * aL[OUT_F + c0 + 1] +
               acc2 * aL[OUT_F + c0 + 2] + acc3 * aL[OUT_F + c0 + 3];
    for (int off = 8; off; off >>= 1) {
        sa += __shfl_xor(sa, off, 16);
        sb += __shfl_xor(sb, off, 16);
    }
    if (tc == 0) { si[row] = sa; sj[row] = sb; }
}

// Ballot-compaction of 4 candidate elements into the LDS neighbor list.
static __device__ __forceinline__ void compact4(
    unsigned int m0, unsigned int m1, unsigned int m2, unsigned int m3,
    int j0, float si, const float* __restrict__ sj_arr, int lane,
    float& lmax, int* s_cnt, int* s_idx, float* s_w) {
#pragma unroll
    for (int u = 0; u < 4; ++u) {
        unsigned int mu = (u == 0) ? m0 : (u == 1) ? m1 : (u == 2) ? m2 : m3;
        bool hit = (mu != 0u);
        unsigned long long b = __ballot(hit);
        if (b) {  // wave-uniform
            int base;
            if (lane == 0) base = atomicAdd(s_cnt, __popcll(b));
            base = __shfl(base, 0, 64);
            if (hit) {
                int j = j0 + u;
                float sc = si + sj_arr[j];
                sc = (sc >= 0.f) ? sc : NEG_SLOPE * sc;
                lmax = fmaxf(lmax, sc);
                int pos = base + __popcll(b & ((1ull << lane) - 1ull));
                if (pos < CAP) { s_idx[pos] = j; s_w[pos] = sc; }
            }
        }
    }
}

// ---------------------------------------------------------------------------
// Fused masked softmax + h_out = attn @ proj. 512 blocks x 16 rows.
// Per row: 8 chunk loads preloaded into registers (8 outstanding vmem ops ->
// one HBM latency per row), ballot compaction, exp/sum, coalesced gather.
// Output dtype follows X's detected dtype (fp32 for this harness).
// ---------------------------------------------------------------------------
__global__ __launch_bounds__(256, 4) void attn_kernel(
    const void* __restrict__ adj, const void* __restrict__ Xv,
    const float* __restrict__ proj, const float* __restrict__ si_arr,
    const float* __restrict__ sj_arr, void* __restrict__ outv) {
    __shared__ int   s_idx[CAP];
    __shared__ float s_w[CAP];
    __shared__ int   s_cnt;
    __shared__ float red[256];
    __shared__ float hacc[OUT_F];
    __shared__ int   sdet[2];

    int tid = threadIdx.x;
    int lane = tid & 63;

    if (tid == 0) { sdet[0] = 0; sdet[1] = 0; }
    __syncthreads();
    block_or(adj_viol_local((const unsigned int*)adj, tid), tid, sdet, 0);
    block_or(x_is_f32_local((const unsigned short*)Xv, tid), tid, sdet, 1);
    __syncthreads();
    int f = sdet[0];
    int width = (!(f & 1)) ? 4 : ((!(f & 2)) ? 2 : 1);
    bool f32o = (sdet[1] != 0);

    for (int rr = 0; rr < ROWS_PER_BLOCK; ++rr) {
        int row = blockIdx.x * ROWS_PER_BLOCK + rr;
        __syncthreads();           // previous row fully done before reusing LDS
        if (tid == 0) s_cnt = 0;
        __syncthreads();

        float si = si_arr[row];
        float lmax = -3.0e38f;

        if (width == 4) {
            const uint4* p = (const uint4*)((const unsigned int*)adj + (size_t)row * N_NODES);
            uint4 c[8];
#pragma unroll
            for (int k = 0; k < 8; ++k) c[k] = p[k * 256 + tid];
#pragma unroll
            for (int k = 0; k < 8; ++k)
                compact4(c[k].x, c[k].y, c[k].z, c[k].w, k * 1024 + tid * 4,
                         si, sj_arr, lane, lmax, &s_cnt, s_idx, s_w);
        } else if (width == 2) {
            const uint2* p = (const uint2*)((const unsigned short*)adj + (size_t)row * N_NODES);
            uint2 c[8];
#pragma unroll
            for (int k = 0; k < 8; ++k) c[k] = p[k * 256 + tid];
#pragma unroll
            for (int k = 0; k < 8; ++k)
                compact4(c[k].x & 0xFFFFu, c[k].x >> 16, c[k].y & 0xFFFFu, c[k].y >> 16,
                         k * 1024 + tid * 4, si, sj_arr, lane, lmax, &s_cnt, s_idx, s_w);
        } else {
            const unsigned int* p = (const unsigned int*)((const unsigned char*)adj + (size_t)row * N_NODES);
            unsigned int c[8];
#pragma unroll
            for (int k = 0; k < 8; ++k) c[k] = p[k * 256 + tid];
#pragma unroll
            for (int k = 0; k < 8; ++k)
                compact4(c[k] & 0xFFu, (c[k] >> 8) & 0xFFu, (c[k] >> 16) & 0xFFu, c[k] >> 24,
                         k * 1024 + tid * 4, si, sj_arr, lane, lmax, &s_cnt, s_idx, s_w);
        }

        red[tid] = lmax;
        __syncthreads();
        int cnt = s_cnt;
        for (int s = 128; s > 0; s >>= 1) {
            if (tid < s) red[tid] = fmaxf(red[tid], red[tid + s]);
            __syncthreads();
        }
        float m = red[0];
        __syncthreads();

        if (cnt == 0) {
            // all-NEG_BIG row -> uniform softmax -> column mean of proj
            int c = tid & 63, part = tid >> 6;
            float acc = 0.f;
#pragma unroll 1
            for (int j = part; j < N_NODES; j += 4) acc += proj[(size_t)j * OUT_F + c];
            red[tid] = acc;
            __syncthreads();
            if (tid < OUT_F) {
                float h = (red[tid] + red[tid + 64] + red[tid + 128] + red[tid + 192]) * (1.0f / N_NODES);
                if (f32o) ((float*)outv)[(size_t)row * OUT_F + tid] = h;
                else ((unsigned short*)outv)[(size_t)row * OUT_F + tid] = f2bf(h);
            }
            continue;
        }

        if (cnt <= CAP) {
            float psum = 0.f;
            for (int k = tid; k < cnt; k += 256) {
                float w = expf(s_w[k] - m);
                s_w[k] = w;
                psum += w;
            }
            red[tid] = psum;
            __syncthreads();
            for (int s = 128; s > 0; s >>= 1) {
                if (tid < s) red[tid] += red[tid + s];
                __syncthreads();
            }
            float denom = red[0];
            __syncthreads();

            int c = tid & 63, part = tid >> 6;
            float acc = 0.f;
            for (int k = part; k < cnt; k += 4)
                acc += s_w[k] * proj[(size_t)s_idx[k] * OUT_F + c];
            red[tid] = acc;
            __syncthreads();
            if (tid < OUT_F) {
                float h = (red[tid] + red[tid + 64] + red[tid + 128] + red[tid + 192]) / denom;
                if (f32o) ((float*)outv)[(size_t)row * OUT_F + tid] = h;
                else ((unsigned short*)outv)[(size_t)row * OUT_F + tid] = f2bf(h);
            }
            continue;
        }

        // ---- overflow fallback (cnt > CAP): correct, slow, never hit ----
        if (tid < OUT_F) hacc[tid] = 0.f;
        __syncthreads();
        float psum = 0.f;
#pragma unroll 1
        for (int j = tid; j < N_NODES; j += 256) {
            unsigned int mu;
            if (width == 4)      mu = ((const unsigned int*)adj)[(size_t)row * N_NODES + j];
            else if (width == 2) mu = ((const unsigned short*)adj)[(size_t)row * N_NODES + j];
            else                 mu = ((const unsigned char*)adj)[(size_t)row * N_NODES + j];
            if (mu) {
                float sc = si + sj_arr[j];
                sc = (sc >= 0.f) ? sc : NEG_SLOPE * sc;
                float w = expf(sc - m);
                psum += w;
#pragma unroll 1
                for (int c = 0; c < OUT_F; ++c)
                    atomicAdd(&hacc[c], w * proj[(size_t)j * OUT_F + c]);
            }
        }
        red[tid] = psum;
        __syncthreads();
        for (int s = 128; s > 0; s >>= 1) {
            if (tid < s) red[tid] += red[tid + s];
            __syncthreads();
        }
        float denom = red[0];
        __syncthreads();
        if (tid < OUT_F) {
            float h = hacc[tid] / denom;
            if (f32o) ((float*)outv)[(size_t)row * OUT_F + tid] = h;
            else ((unsigned short*)outv)[(size_t)row * OUT_F + tid] = f2bf(h);
        }
    }
}

extern "C" void kernel_launch(void* const* d_in, const int* in_sizes, int n_in,
                              void* d_out, int out_size, void* d_ws, size_t ws_size,
                              hipStream_t stream) {
    const void* X   = d_in[0];  // [8192,256] fp32 (runtime-detected; bf16 fallback)
    const void* adj = d_in[1];  // [8192,8192] bool, width runtime-detected
    const void* W   = d_in[2];  // [256,64]
    const void* A   = d_in[3];  // [128,1]

    char* ws = (char*)d_ws;
    float* si   = (float*)ws;
    float* sj   = (float*)(ws + 32768);
    float* proj = (float*)(ws + 65536);

    proj_kernel<<<N_NODES / 16, 256, 0, stream>>>(X, W, A, proj, si, sj);
    attn_kernel<<<N_NODES / ROWS_PER_BLOCK, 256, 0, stream>>>(adj, X, proj, si, sj, d_out);
}

// Round 6
// 418.779 us; speedup vs baseline: 1.2991x; 1.2991x over previous
//
#include <hip/hip_runtime.h>
#include <hip/hip_bf16.h>
#include <stdint.h>

#define N_NODES 8192
#define IN_F    256
#define OUT_F   64
#define NEG_SLOPE 0.2f
#define CAP     512       // per-wave neighbor list; mean degree 82, sd 9 -> 47 sigma
#define DET_WORDS  4096   // 16 KB adjacency prefix scanned per block (L2-cached)
#define DET_HALVES 8192   // 16 KB X prefix scanned per block

static __device__ __forceinline__ float bf2f(unsigned short u) {
    union { unsigned int i; float f; } v; v.i = ((unsigned int)u) << 16; return v.f;
}
static __device__ __forceinline__ float bflo(unsigned int u) {
    union { unsigned int i; float f; } v; v.i = u << 16; return v.f;
}
static __device__ __forceinline__ float bfhi(unsigned int u) {
    union { unsigned int i; float f; } v; v.i = u & 0xFFFF0000u; return v.f;
}
static __device__ __forceinline__ unsigned short f2bf(float f) {
    union { float f; unsigned int i; } v; v.f = f;
    unsigned int x = v.i;
    unsigned int lsb = (x >> 16) & 1u;
    x += 0x7FFFu + lsb;
    return (unsigned short)(x >> 16);
}

// Adjacency element-width detection on the shared 16KB prefix. Violation
// bits: bit0 = not 4-byte elems (words in {0,1,0x3F800000}), bit1 = not
// 2-byte, bit2 = not 1-byte. Width = 4 if !bit0 else 2 if !bit1 else 1.
// R5 counters (FETCH 167MB) confirm width=4 for this harness.
static __device__ __forceinline__ int adj_viol_local(const unsigned int* w, int tid) {
    int viol = 0;
    for (int i = tid; i < DET_WORDS; i += 256) {
        unsigned int v = w[i];
        if (v) {
            if (v != 1u && v != 0x3F800000u) viol |= 1;
            unsigned int h0 = v & 0xFFFFu, h1 = v >> 16;
            if ((h0 != 0u && h0 != 1u && h0 != 0x3F80u) ||
                (h1 != 0u && h1 != 1u && h1 != 0x3F80u)) viol |= 2;
            unsigned int b0 = v & 0xFFu, b1 = (v >> 8) & 0xFFu,
                         b2 = (v >> 16) & 0xFFu, b3 = v >> 24;
            if (b0 > 1u || b1 > 1u || b2 > 1u || b3 > 1u) viol |= 4;
        }
    }
    return viol;
}

// X dtype: nonzero => fp32 (bf16-exponent >= 133 never occurs in bf16 N(0,1)
// data, occurs w.p. ~0.48 per fp32 mantissa half). R5: fp32 for this harness.
static __device__ __forceinline__ int x_is_f32_local(const unsigned short* x, int tid) {
    int viol = 0;
    for (int i = tid; i < DET_HALVES; i += 256) {
        unsigned int e = ((unsigned int)x[i] >> 7) & 0xFFu;
        if (e >= 133u) viol = 1;
    }
    return viol;
}

static __device__ __forceinline__ void block_or(int v, int tid, int* sdet, int slot) {
    for (int o = 32; o; o >>= 1) v |= __shfl_xor(v, o, 64);
    if ((tid & 63) == 0 && v) atomicOr(&sdet[slot], v);
}

// ---------------------------------------------------------------------------
// proj = X @ W (fp32 accum), s_i = proj @ a[:64], s_j = proj @ a[64:]
// 512 blocks x 16 rows. Thread t: row=t>>4, cols (t&15)*4..+3. (R5-verified)
// ---------------------------------------------------------------------------
__global__ __launch_bounds__(256) void proj_kernel(
    const void* __restrict__ Xv, const void* __restrict__ Wv,
    const void* __restrict__ Av,
    float* __restrict__ proj, float* __restrict__ si, float* __restrict__ sj) {
    __shared__ unsigned short wL[IN_F * OUT_F];  // 32 KB
    __shared__ unsigned short xL[16 * IN_F];     // 8 KB
    __shared__ float aL[2 * OUT_F];
    __shared__ int sdet[2];

    int tid = threadIdx.x;
    if (tid == 0) { sdet[0] = 0; sdet[1] = 0; }
    __syncthreads();
    block_or(x_is_f32_local((const unsigned short*)Xv, tid), tid, sdet, 1);
    __syncthreads();
    bool xf32 = (sdet[1] != 0);

    int row0 = blockIdx.x * 16;
    int tc = tid & 15;
    int r  = tid >> 4;
    int c0 = tc * 4;
    int row = row0 + r;

    float acc0 = 0.f, acc1 = 0.f, acc2 = 0.f, acc3 = 0.f;

    if (xf32) {
        const float* Xf = (const float*)Xv;
        const float* Wf = (const float*)Wv;
        const float* Af = (const float*)Av;
        if (tid < 2 * OUT_F) aL[tid] = Af[tid];
        __syncthreads();
        const float4* xr = (const float4*)(Xf + (size_t)row * IN_F);
#pragma unroll 2
        for (int kv = 0; kv < IN_F / 4; ++kv) {
            float4 xq = xr[kv];
#pragma unroll
            for (int t = 0; t < 4; ++t) {
                float x = (t == 0) ? xq.x : (t == 1) ? xq.y : (t == 2) ? xq.z : xq.w;
                float4 wq = *(const float4*)(Wf + (size_t)(kv * 4 + t) * OUT_F + c0);
                acc0 = fmaf(x, wq.x, acc0);
                acc1 = fmaf(x, wq.y, acc1);
                acc2 = fmaf(x, wq.z, acc2);
                acc3 = fmaf(x, wq.w, acc3);
            }
        }
    } else {
        const unsigned short* Xh = (const unsigned short*)Xv;
        const unsigned short* Wh = (const unsigned short*)Wv;
        const unsigned short* Ah = (const unsigned short*)Av;
        for (int i = tid; i < (IN_F * OUT_F) / 8; i += 256)
            ((uint4*)wL)[i] = ((const uint4*)Wh)[i];
        for (int i = tid; i < (16 * IN_F) / 8; i += 256)
            ((uint4*)xL)[i] = ((const uint4*)(Xh + (size_t)row0 * IN_F))[i];
        if (tid < 2 * OUT_F) aL[tid] = bf2f(Ah[tid]);
        __syncthreads();

        const uint4* xrv = (const uint4*)&xL[r * IN_F];
#pragma unroll 4
        for (int kv = 0; kv < IN_F / 8; ++kv) {
            uint4 xq = xrv[kv];
#pragma unroll
            for (int h = 0; h < 4; ++h) {
                unsigned int xp = (h == 0) ? xq.x : (h == 1) ? xq.y : (h == 2) ? xq.z : xq.w;
                int k0 = kv * 8 + h * 2;
                uint2 w0 = *(const uint2*)&wL[(k0 + 0) * OUT_F + c0];
                uint2 w1 = *(const uint2*)&wL[(k0 + 1) * OUT_F + c0];
                float xa = bflo(xp), xb = bfhi(xp);
                acc0 = fmaf(xa, bflo(w0.x), acc0);
                acc1 = fmaf(xa, bfhi(w0.x), acc1);
                acc2 = fmaf(xa, bflo(w0.y), acc2);
                acc3 = fmaf(xa, bfhi(w0.y), acc3);
                acc0 = fmaf(xb, bflo(w1.x), acc0);
                acc1 = fmaf(xb, bfhi(w1.x), acc1);
                acc2 = fmaf(xb, bflo(w1.y), acc2);
                acc3 = fmaf(xb, bfhi(w1.y), acc3);
            }
        }
    }

    *(float4*)&proj[(size_t)row * OUT_F + c0] = make_float4(acc0, acc1, acc2, acc3);

    float sa = acc0 * aL[c0] + acc1 * aL[c0 + 1] + acc2 * aL[c0 + 2] + acc3 * aL[c0 + 3];
    float sb = acc0 * aL[OUT_F + c0] + acc1 * aL[OUT_F + c0 + 1] +
               acc2 * aL[OUT_F + c0 + 2] + acc3 * aL[OUT_F + c0 + 3];
    for (int off = 8; off; off >>= 1) {
        sa += __shfl_xor(sa, off, 16);
        sb += __shfl_xor(sb, off, 16);
    }
    if (tc == 0) { si[row] = sa; sj[row] = sb; }
}

// One element per lane: ballot-compact into the per-wave LDS pair list.
// `base` is the wave-uniform running neighbor count (no atomics).
static __device__ __forceinline__ void compact_elem(
    bool hit, int j, float si, const float* __restrict__ sj_arr, int lane,
    float& lmax, int& base, int2* __restrict__ pair) {
    unsigned long long b = __ballot(hit);
    if (b) {
        if (hit) {
            float sc = si + sj_arr[j];
            sc = (sc >= 0.f) ? sc : NEG_SLOPE * sc;
            lmax = fmaxf(lmax, sc);
            int pos = base + (int)__popcll(b & ((1ull << lane) - 1ull));
            if (pos < CAP) pair[pos] = make_int2(j, __float_as_int(sc));
        }
        base += (int)__popcll(b);
    }
}

// ---------------------------------------------------------------------------
// Fused masked softmax + h_out = attn @ proj. ONE ROW PER WAVE.
// 2048 blocks x 4 waves; no barriers or atomics in the row path; shuffle
// reductions; per-wave 4KB LDS pair list. 8 blocks/CU (wave-limited).
// ---------------------------------------------------------------------------
__global__ __launch_bounds__(256, 8) void attn_kernel(
    const void* __restrict__ adj, const void* __restrict__ Xv,
    const float* __restrict__ proj, const float* __restrict__ si_arr,
    const float* __restrict__ sj_arr, void* __restrict__ outv) {
    __shared__ int2 s_pair[4 * CAP];   // 16 KB, 4 KB per wave
    __shared__ int  sdet[2];

    int tid  = threadIdx.x;
    int lane = tid & 63;
    int wid  = tid >> 6;

    if (tid == 0) { sdet[0] = 0; sdet[1] = 0; }
    __syncthreads();
    block_or(adj_viol_local((const unsigned int*)adj, tid), tid, sdet, 0);
    block_or(x_is_f32_local((const unsigned short*)Xv, tid), tid, sdet, 1);
    __syncthreads();
    int f = sdet[0];
    int width = (!(f & 1)) ? 4 : ((!(f & 2)) ? 2 : 1);
    bool f32o = (sdet[1] != 0);

    int row = blockIdx.x * 4 + wid;
    int2* pair = &s_pair[wid * CAP];

    float si = si_arr[row];
    float lmax = -3.0e38f;
    int base = 0;   // wave-uniform neighbor count

    if (width == 4) {
        const uint4* p = (const uint4*)((const unsigned int*)adj + (size_t)row * N_NODES);
#pragma unroll 1
        for (int it = 0; it < 8; ++it) {
            int v0 = it * 256 + lane;
            uint4 c0 = p[v0];
            uint4 c1 = p[v0 + 64];
            uint4 c2 = p[v0 + 128];
            uint4 c3 = p[v0 + 192];
#pragma unroll
            for (int q = 0; q < 4; ++q) {
                uint4 c = (q == 0) ? c0 : (q == 1) ? c1 : (q == 2) ? c2 : c3;
                int j0 = 4 * (v0 + q * 64);
                compact_elem(c.x != 0u, j0 + 0, si, sj_arr, lane, lmax, base, pair);
                compact_elem(c.y != 0u, j0 + 1, si, sj_arr, lane, lmax, base, pair);
                compact_elem(c.z != 0u, j0 + 2, si, sj_arr, lane, lmax, base, pair);
                compact_elem(c.w != 0u, j0 + 3, si, sj_arr, lane, lmax, base, pair);
            }
        }
    } else if (width == 2) {
        const uint4* p = (const uint4*)((const unsigned short*)adj + (size_t)row * N_NODES);
#pragma unroll 1
        for (int it = 0; it < 4; ++it) {
            int v0 = it * 256 + lane;
            uint4 c0 = p[v0];
            uint4 c1 = p[v0 + 64];
            uint4 c2 = p[v0 + 128];
            uint4 c3 = p[v0 + 192];
#pragma unroll
            for (int q = 0; q < 4; ++q) {
                uint4 c = (q == 0) ? c0 : (q == 1) ? c1 : (q == 2) ? c2 : c3;
                int j0 = 8 * (v0 + q * 64);
#pragma unroll
                for (int h = 0; h < 4; ++h) {
                    unsigned int word = (h == 0) ? c.x : (h == 1) ? c.y : (h == 2) ? c.z : c.w;
                    compact_elem((word & 0xFFFFu) != 0u, j0 + 2 * h + 0, si, sj_arr, lane, lmax, base, pair);
                    compact_elem((word >> 16)     != 0u, j0 + 2 * h + 1, si, sj_arr, lane, lmax, base, pair);
                }
            }
        }
    } else {
        const uint4* p = (const uint4*)((const unsigned char*)adj + (size_t)row * N_NODES);
#pragma unroll 1
        for (int it = 0; it < 2; ++it) {
            int v0 = it * 256 + lane;
            uint4 c0 = p[v0];
            uint4 c1 = p[v0 + 64];
            uint4 c2 = p[v0 + 128];
            uint4 c3 = p[v0 + 192];
#pragma unroll
            for (int q = 0; q < 4; ++q) {
                uint4 c = (q == 0) ? c0 : (q == 1) ? c1 : (q == 2) ? c2 : c3;
                int j0 = 16 * (v0 + q * 64);
#pragma unroll
                for (int h = 0; h < 4; ++h) {
                    unsigned int word = (h == 0) ? c.x : (h == 1) ? c.y : (h == 2) ? c.z : c.w;
                    compact_elem(((word)       & 0xFFu) != 0u, j0 + 4 * h + 0, si, sj_arr, lane, lmax, base, pair);
                    compact_elem(((word >> 8)  & 0xFFu) != 0u, j0 + 4 * h + 1, si, sj_arr, lane, lmax, base, pair);
                    compact_elem(((word >> 16) & 0xFFu) != 0u, j0 + 4 * h + 2, si, sj_arr, lane, lmax, base, pair);
                    compact_elem(((word >> 24)       ) != 0u, j0 + 4 * h + 3, si, sj_arr, lane, lmax, base, pair);
                }
            }
        }
    }

    // wave max
    for (int o = 32; o; o >>= 1) lmax = fmaxf(lmax, __shfl_xor(lmax, o, 64));
    float m = lmax;

    if (base == 0) {
        // all-NEG_BIG row -> uniform softmax -> column mean of proj
        float acc = 0.f;
#pragma unroll 4
        for (int j = 0; j < N_NODES; ++j) acc += proj[(size_t)j * OUT_F + lane];
        float h = acc * (1.0f / (float)N_NODES);
        if (f32o) ((float*)outv)[(size_t)row * OUT_F + lane] = h;
        else ((unsigned short*)outv)[(size_t)row * OUT_F + lane] = f2bf(h);
        return;
    }

    if (base <= CAP) {
        int cnt = base;
        // exp + wave sum (LDS written/read by this wave only; in-order)
        float psum = 0.f;
        for (int k = lane; k < cnt; k += 64) {
            int2 pr = pair[k];
            float w = expf(__int_as_float(pr.y) - m);
            pair[k].y = __float_as_int(w);
            psum += w;
        }
        for (int o = 32; o; o >>= 1) psum += __shfl_xor(psum, o, 64);
        float inv_denom = 1.0f / psum;

        // gather: lane = output column; pair[k] reads are wave-uniform broadcasts
        float acc = 0.f;
#pragma unroll 4
        for (int k = 0; k < cnt; ++k) {
            int2 pr = pair[k];
            acc = fmaf(__int_as_float(pr.y), proj[(size_t)pr.x * OUT_F + lane], acc);
        }
        float h = acc * inv_denom;
        if (f32o) ((float*)outv)[(size_t)row * OUT_F + lane] = h;
        else ((unsigned short*)outv)[(size_t)row * OUT_F + lane] = f2bf(h);
        return;
    }

    // ---- overflow fallback (base > CAP): correct, slow, statistically never hit.
    // m is exact (tracked over all hits). All lanes recompute w identically;
    // psum needs no reduction. lane = output column.
    float psum = 0.f, acc = 0.f;
#pragma unroll 1
    for (int j = 0; j < N_NODES; ++j) {
        unsigned int mu;
        if (width == 4)      mu = ((const unsigned int*)adj)[(size_t)row * N_NODES + j];
        else if (width == 2) mu = ((const unsigned short*)adj)[(size_t)row * N_NODES + j];
        else                 mu = ((const unsigned char*)adj)[(size_t)row * N_NODES + j];
        if (mu) {
            float sc = si + sj_arr[j];
            sc = (sc >= 0.f) ? sc : NEG_SLOPE * sc;
            float w = expf(sc - m);
            psum += w;
            acc = fmaf(w, proj[(size_t)j * OUT_F + lane], acc);
        }
    }
    float h = acc / psum;
    if (f32o) ((float*)outv)[(size_t)row * OUT_F + lane] = h;
    else ((unsigned short*)outv)[(size_t)row * OUT_F + lane] = f2bf(h);
}

extern "C" void kernel_launch(void* const* d_in, const int* in_sizes, int n_in,
                              void* d_out, int out_size, void* d_ws, size_t ws_size,
                              hipStream_t stream) {
    const void* X   = d_in[0];  // [8192,256] fp32 (runtime-detected; bf16 fallback)
    const void* adj = d_in[1];  // [8192,8192] bool as int32 (runtime-detected)
    const void* W   = d_in[2];  // [256,64]
    const void* A   = d_in[3];  // [128,1]

    char* ws = (char*)d_ws;
    float* si   = (float*)ws;
    float* sj   = (float*)(ws + 32768);
    float* proj = (float*)(ws + 65536);

    proj_kernel<<<N_NODES / 16, 256, 0, stream>>>(X, W, A, proj, si, sj);
    attn_kernel<<<N_NODES / 4, 256, 0, stream>>>(adj, X, proj, si, sj, d_out);
}

// Round 7
// 410.705 us; speedup vs baseline: 1.3246x; 1.0197x over previous
//
#include <hip/hip_runtime.h>
#include <hip/hip_bf16.h>
#include <stdint.h>

#define N_NODES 8192
#define IN_F    256
#define OUT_F   64
#define NEG_SLOPE 0.2f
#define CAP     512       // per-wave neighbor list; mean degree 82, sd 9 -> 47 sigma
#define DET_WORDS  4096   // 16 KB adjacency prefix scanned per block (L2-cached)
#define DET_HALVES 8192   // 16 KB X prefix scanned per block

static __device__ __forceinline__ float bf2f(unsigned short u) {
    union { unsigned int i; float f; } v; v.i = ((unsigned int)u) << 16; return v.f;
}
static __device__ __forceinline__ float bflo(unsigned int u) {
    union { unsigned int i; float f; } v; v.i = u << 16; return v.f;
}
static __device__ __forceinline__ float bfhi(unsigned int u) {
    union { unsigned int i; float f; } v; v.i = u & 0xFFFF0000u; return v.f;
}
static __device__ __forceinline__ unsigned short f2bf(float f) {
    union { float f; unsigned int i; } v; v.f = f;
    unsigned int x = v.i;
    unsigned int lsb = (x >> 16) & 1u;
    x += 0x7FFFu + lsb;
    return (unsigned short)(x >> 16);
}

// Adjacency element-width detection on the shared 16KB prefix. Violation
// bits: bit0 = not 4-byte elems, bit1 = not 2-byte, bit2 = not 1-byte.
// Width = 4 if !bit0 else 2 if !bit1 else 1. (R5 FETCH=167MB => width 4.)
static __device__ __forceinline__ int adj_viol_local(const unsigned int* w, int tid) {
    int viol = 0;
    for (int i = tid; i < DET_WORDS; i += 256) {
        unsigned int v = w[i];
        if (v) {
            if (v != 1u && v != 0x3F800000u) viol |= 1;
            unsigned int h0 = v & 0xFFFFu, h1 = v >> 16;
            if ((h0 != 0u && h0 != 1u && h0 != 0x3F80u) ||
                (h1 != 0u && h1 != 1u && h1 != 0x3F80u)) viol |= 2;
            unsigned int b0 = v & 0xFFu, b1 = (v >> 8) & 0xFFu,
                         b2 = (v >> 16) & 0xFFu, b3 = v >> 24;
            if (b0 > 1u || b1 > 1u || b2 > 1u || b3 > 1u) viol |= 4;
        }
    }
    return viol;
}

// X dtype: nonzero => fp32 (bf16-exponent >= 133 occurs w.p. ~0.48 per fp32
// mantissa half, never in bf16 N(0,1)). R5: fp32 for this harness.
static __device__ __forceinline__ int x_is_f32_local(const unsigned short* x, int tid) {
    int viol = 0;
    for (int i = tid; i < DET_HALVES; i += 256) {
        unsigned int e = ((unsigned int)x[i] >> 7) & 0xFFu;
        if (e >= 133u) viol = 1;
    }
    return viol;
}

static __device__ __forceinline__ void block_or(int v, int tid, int* sdet, int slot) {
    for (int o = 32; o; o >>= 1) v |= __shfl_xor(v, o, 64);
    if ((tid & 63) == 0 && v) atomicOr(&sdet[slot], v);
}

// ---------------------------------------------------------------------------
// proj = X @ W (fp32 accum), s_i = proj @ a[:64], s_j = proj @ a[64:]
// 512 blocks x 16 rows. Thread t: row=t>>4, cols (t&15)*4..+3. (R5-verified)
// ---------------------------------------------------------------------------
__global__ __launch_bounds__(256) void proj_kernel(
    const void* __restrict__ Xv, const void* __restrict__ Wv,
    const void* __restrict__ Av,
    float* __restrict__ proj, float* __restrict__ si, float* __restrict__ sj) {
    __shared__ unsigned short wL[IN_F * OUT_F];  // 32 KB
    __shared__ unsigned short xL[16 * IN_F];     // 8 KB
    __shared__ float aL[2 * OUT_F];
    __shared__ int sdet[2];

    int tid = threadIdx.x;
    if (tid == 0) { sdet[0] = 0; sdet[1] = 0; }
    __syncthreads();
    block_or(x_is_f32_local((const unsigned short*)Xv, tid), tid, sdet, 1);
    __syncthreads();
    bool xf32 = (sdet[1] != 0);

    int row0 = blockIdx.x * 16;
    int tc = tid & 15;
    int r  = tid >> 4;
    int c0 = tc * 4;
    int row = row0 + r;

    float acc0 = 0.f, acc1 = 0.f, acc2 = 0.f, acc3 = 0.f;

    if (xf32) {
        const float* Xf = (const float*)Xv;
        const float* Wf = (const float*)Wv;
        const float* Af = (const float*)Av;
        if (tid < 2 * OUT_F) aL[tid] = Af[tid];
        __syncthreads();
        const float4* xr = (const float4*)(Xf + (size_t)row * IN_F);
#pragma unroll 2
        for (int kv = 0; kv < IN_F / 4; ++kv) {
            float4 xq = xr[kv];
#pragma unroll
            for (int t = 0; t < 4; ++t) {
                float x = (t == 0) ? xq.x : (t == 1) ? xq.y : (t == 2) ? xq.z : xq.w;
                float4 wq = *(const float4*)(Wf + (size_t)(kv * 4 + t) * OUT_F + c0);
                acc0 = fmaf(x, wq.x, acc0);
                acc1 = fmaf(x, wq.y, acc1);
                acc2 = fmaf(x, wq.z, acc2);
                acc3 = fmaf(x, wq.w, acc3);
            }
        }
    } else {
        const unsigned short* Xh = (const unsigned short*)Xv;
        const unsigned short* Wh = (const unsigned short*)Wv;
        const unsigned short* Ah = (const unsigned short*)Av;
        for (int i = tid; i < (IN_F * OUT_F) / 8; i += 256)
            ((uint4*)wL)[i] = ((const uint4*)Wh)[i];
        for (int i = tid; i < (16 * IN_F) / 8; i += 256)
            ((uint4*)xL)[i] = ((const uint4*)(Xh + (size_t)row0 * IN_F))[i];
        if (tid < 2 * OUT_F) aL[tid] = bf2f(Ah[tid]);
        __syncthreads();

        const uint4* xrv = (const uint4*)&xL[r * IN_F];
#pragma unroll 4
        for (int kv = 0; kv < IN_F / 8; ++kv) {
            uint4 xq = xrv[kv];
#pragma unroll
            for (int h = 0; h < 4; ++h) {
                unsigned int xp = (h == 0) ? xq.x : (h == 1) ? xq.y : (h == 2) ? xq.z : xq.w;
                int k0 = kv * 8 + h * 2;
                uint2 w0 = *(const uint2*)&wL[(k0 + 0) * OUT_F + c0];
                uint2 w1 = *(const uint2*)&wL[(k0 + 1) * OUT_F + c0];
                float xa = bflo(xp), xb = bfhi(xp);
                acc0 = fmaf(xa, bflo(w0.x), acc0);
                acc1 = fmaf(xa, bfhi(w0.x), acc1);
                acc2 = fmaf(xa, bflo(w0.y), acc2);
                acc3 = fmaf(xa, bfhi(w0.y), acc3);
                acc0 = fmaf(xb, bflo(w1.x), acc0);
                acc1 = fmaf(xb, bfhi(w1.x), acc1);
                acc2 = fmaf(xb, bflo(w1.y), acc2);
                acc3 = fmaf(xb, bfhi(w1.y), acc3);
            }
        }
    }

    *(float4*)&proj[(size_t)row * OUT_F + c0] = make_float4(acc0, acc1, acc2, acc3);

    float sa = acc0 * aL[c0] + acc1 * aL[c0 + 1] + acc2 * aL[c0 + 2] + acc3 * aL[c0 + 3];
    float sb = acc0 * aL[OUT_F + c0] + acc1 * aL[OUT_F + c0 + 1] +
               acc2 * aL[OUT_F + c0 + 2] + acc3 * aL[OUT_F + c0 + 3];
    for (int off = 8; off; off >>= 1) {
        sa += __shfl_xor(sa, off, 16);
        sb += __shfl_xor(sb, off, 16);
    }
    if (tc == 0) { si[row] = sa; sj[row] = sb; }
}

// Index-only ballot compaction: no global loads, no score math in the scan.
static __device__ __forceinline__ void compact_idx(
    bool hit, int j, int lane, unsigned long long mask_lt,
    int& base, int* __restrict__ idxL) {
    unsigned long long b = __ballot(hit);
    if (hit) {
        int pos = base + (int)__popcll(b & mask_lt);
        if (pos < CAP) idxL[pos] = j;
    }
    base += (int)__popcll(b);
}

// ---------------------------------------------------------------------------
// Fused masked softmax + h_out = attn @ proj. ONE ROW PER WAVE.
// Scan phase is a pure adjacency stream (prefetch-pipelined dwordx4 loads,
// index-only compaction). Scores/max/exp computed afterwards from the
// compacted list (<=2 parallel sj gathers per lane). No barriers/atomics in
// the row path. 2048 blocks x 4 waves; 8 blocks/CU.
// ---------------------------------------------------------------------------
__global__ __launch_bounds__(256, 8) void attn_kernel(
    const void* __restrict__ adj, const void* __restrict__ Xv,
    const float* __restrict__ proj, const float* __restrict__ si_arr,
    const float* __restrict__ sj_arr, void* __restrict__ outv) {
    __shared__ int   s_idx[4 * CAP];   // 8 KB (2 KB per wave)
    __shared__ float s_sc[4 * CAP];    // 8 KB (2 KB per wave)
    __shared__ int   sdet[2];

    int tid  = threadIdx.x;
    int lane = tid & 63;
    int wid  = tid >> 6;

    if (tid == 0) { sdet[0] = 0; sdet[1] = 0; }
    __syncthreads();
    block_or(adj_viol_local((const unsigned int*)adj, tid), tid, sdet, 0);
    block_or(x_is_f32_local((const unsigned short*)Xv, tid), tid, sdet, 1);
    __syncthreads();
    int f = sdet[0];
    int width = (!(f & 1)) ? 4 : ((!(f & 2)) ? 2 : 1);
    bool f32o = (sdet[1] != 0);

    int row = blockIdx.x * 4 + wid;
    int*   idxL = &s_idx[wid * CAP];
    float* scL  = &s_sc[wid * CAP];

    unsigned long long mask_lt = (1ull << lane) - 1ull;
    float si = si_arr[row];
    int base = 0;   // wave-uniform neighbor count

    if (width == 4) {
        const uint4* p = (const uint4*)((const unsigned int*)adj + (size_t)row * N_NODES);
        uint4 c0 = p[lane], c1 = p[lane + 64], c2 = p[lane + 128], c3 = p[lane + 192];
#pragma unroll 1
        for (int it = 0; it < 8; ++it) {
            uint4 n0, n1, n2, n3;
            if (it < 7) {
                int v = (it + 1) * 256 + lane;
                n0 = p[v]; n1 = p[v + 64]; n2 = p[v + 128]; n3 = p[v + 192];
            }
#pragma unroll
            for (int q = 0; q < 4; ++q) {
                uint4 c = (q == 0) ? c0 : (q == 1) ? c1 : (q == 2) ? c2 : c3;
                int j0 = 4 * (it * 256 + lane + q * 64);
                compact_idx(c.x != 0u, j0 + 0, lane, mask_lt, base, idxL);
                compact_idx(c.y != 0u, j0 + 1, lane, mask_lt, base, idxL);
                compact_idx(c.z != 0u, j0 + 2, lane, mask_lt, base, idxL);
                compact_idx(c.w != 0u, j0 + 3, lane, mask_lt, base, idxL);
            }
            c0 = n0; c1 = n1; c2 = n2; c3 = n3;
        }
    } else if (width == 2) {
        const uint4* p = (const uint4*)((const unsigned short*)adj + (size_t)row * N_NODES);
#pragma unroll 1
        for (int it = 0; it < 4; ++it) {
            int v0 = it * 256 + lane;
            uint4 c0 = p[v0], c1 = p[v0 + 64], c2 = p[v0 + 128], c3 = p[v0 + 192];
#pragma unroll
            for (int q = 0; q < 4; ++q) {
                uint4 c = (q == 0) ? c0 : (q == 1) ? c1 : (q == 2) ? c2 : c3;
                int j0 = 8 * (v0 + q * 64);
#pragma unroll
                for (int h = 0; h < 4; ++h) {
                    unsigned int word = (h == 0) ? c.x : (h == 1) ? c.y : (h == 2) ? c.z : c.w;
                    compact_idx((word & 0xFFFFu) != 0u, j0 + 2 * h + 0, lane, mask_lt, base, idxL);
                    compact_idx((word >> 16)     != 0u, j0 + 2 * h + 1, lane, mask_lt, base, idxL);
                }
            }
        }
    } else {
        const uint4* p = (const uint4*)((const unsigned char*)adj + (size_t)row * N_NODES);
#pragma unroll 1
        for (int it = 0; it < 2; ++it) {
            int v0 = it * 256 + lane;
            uint4 c0 = p[v0], c1 = p[v0 + 64], c2 = p[v0 + 128], c3 = p[v0 + 192];
#pragma unroll
            for (int q = 0; q < 4; ++q) {
                uint4 c = (q == 0) ? c0 : (q == 1) ? c1 : (q == 2) ? c2 : c3;
                int j0 = 16 * (v0 + q * 64);
#pragma unroll
                for (int h = 0; h < 4; ++h) {
                    unsigned int word = (h == 0) ? c.x : (h == 1) ? c.y : (h == 2) ? c.z : c.w;
                    compact_idx(((word)       & 0xFFu) != 0u, j0 + 4 * h + 0, lane, mask_lt, base, idxL);
                    compact_idx(((word >> 8)  & 0xFFu) != 0u, j0 + 4 * h + 1, lane, mask_lt, base, idxL);
                    compact_idx(((word >> 16) & 0xFFu) != 0u, j0 + 4 * h + 2, lane, mask_lt, base, idxL);
                    compact_idx(((word >> 24)        ) != 0u, j0 + 4 * h + 3, lane, mask_lt, base, idxL);
                }
            }
        }
    }

    int cnt = base;

    if (cnt == 0) {
        // all-NEG_BIG row -> uniform softmax -> column mean of proj (never hit)
        float acc = 0.f;
#pragma unroll 4
        for (int j = 0; j < N_NODES; ++j) acc += proj[(size_t)j * OUT_F + lane];
        float h = acc * (1.0f / (float)N_NODES);
        if (f32o) ((float*)outv)[(size_t)row * OUT_F + lane] = h;
        else ((unsigned short*)outv)[(size_t)row * OUT_F + lane] = f2bf(h);
        return;
    }

    if (cnt <= CAP) {
        // phase 2: batched score computation — <=2 independent sj gathers/lane
        float m = -3.0e38f;
        for (int k = lane; k < cnt; k += 64) {
            int j = idxL[k];
            float sc = si + sj_arr[j];
            sc = (sc >= 0.f) ? sc : NEG_SLOPE * sc;
            scL[k] = sc;
            m = fmaxf(m, sc);
        }
        for (int o = 32; o; o >>= 1) m = fmaxf(m, __shfl_xor(m, o, 64));

        float psum = 0.f;
        for (int k = lane; k < cnt; k += 64) {
            float w = expf(scL[k] - m);
            scL[k] = w;
            psum += w;
        }
        for (int o = 32; o; o >>= 1) psum += __shfl_xor(psum, o, 64);
        float inv_denom = 1.0f / psum;

        // phase 3: gather — lane = column; idxL/scL reads are LDS broadcasts
        float acc = 0.f;
#pragma unroll 4
        for (int k = 0; k < cnt; ++k)
            acc = fmaf(scL[k], proj[(size_t)idxL[k] * OUT_F + lane], acc);
        float h = acc * inv_denom;
        if (f32o) ((float*)outv)[(size_t)row * OUT_F + lane] = h;
        else ((unsigned short*)outv)[(size_t)row * OUT_F + lane] = f2bf(h);
        return;
    }

    // ---- overflow fallback (cnt > CAP): correct, slow, statistically never hit.
    float m = -3.0e38f;
#pragma unroll 1
    for (int j = lane; j < N_NODES; j += 64) {
        unsigned int mu;
        if (width == 4)      mu = ((const unsigned int*)adj)[(size_t)row * N_NODES + j];
        else if (width == 2) mu = ((const unsigned short*)adj)[(size_t)row * N_NODES + j];
        else                 mu = ((const unsigned char*)adj)[(size_t)row * N_NODES + j];
        if (mu) {
            float sc = si + sj_arr[j];
            sc = (sc >= 0.f) ? sc : NEG_SLOPE * sc;
            m = fmaxf(m, sc);
        }
    }
    for (int o = 32; o; o >>= 1) m = fmaxf(m, __shfl_xor(m, o, 64));
    float psum = 0.f;
#pragma unroll 1
    for (int j = lane; j < N_NODES; j += 64) {
        unsigned int mu;
        if (width == 4)      mu = ((const unsigned int*)adj)[(size_t)row * N_NODES + j];
        else if (width == 2) mu = ((const unsigned short*)adj)[(size_t)row * N_NODES + j];
        else                 mu = ((const unsigned char*)adj)[(size_t)row * N_NODES + j];
        if (mu) {
            float sc = si + sj_arr[j];
            sc = (sc >= 0.f) ? sc : NEG_SLOPE * sc;
            psum += expf(sc - m);
        }
    }
    for (int o = 32; o; o >>= 1) psum += __shfl_xor(psum, o, 64);
    float acc = 0.f;
#pragma unroll 1
    for (int j = 0; j < N_NODES; ++j) {
        unsigned int mu;
        if (width == 4)      mu = ((const unsigned int*)adj)[(size_t)row * N_NODES + j];
        else if (width == 2) mu = ((const unsigned short*)adj)[(size_t)row * N_NODES + j];
        else                 mu = ((const unsigned char*)adj)[(size_t)row * N_NODES + j];
        if (mu) {
            float sc = si + sj_arr[j];
            sc = (sc >= 0.f) ? sc : NEG_SLOPE * sc;
            acc = fmaf(expf(sc - m), proj[(size_t)j * OUT_F + lane], acc);
        }
    }
    float h = acc / psum;
    if (f32o) ((float*)outv)[(size_t)row * OUT_F + lane] = h;
    else ((unsigned short*)outv)[(size_t)row * OUT_F + lane] = f2bf(h);
}

extern "C" void kernel_launch(void* const* d_in, const int* in_sizes, int n_in,
                              void* d_out, int out_size, void* d_ws, size_t ws_size,
                              hipStream_t stream) {
    const void* X   = d_in[0];  // [8192,256] fp32 (runtime-detected; bf16 fallback)
    const void* adj = d_in[1];  // [8192,8192] bool as int32 (runtime-detected)
    const void* W   = d_in[2];  // [256,64]
    const void* A   = d_in[3];  // [128,1]

    char* ws = (char*)d_ws;
    float* si   = (float*)ws;
    float* sj   = (float*)(ws + 32768);
    float* proj = (float*)(ws + 65536);

    proj_kernel<<<N_NODES / 16, 256, 0, stream>>>(X, W, A, proj, si, sj);
    attn_kernel<<<N_NODES / 4, 256, 0, stream>>>(adj, X, proj, si, sj, d_out);
}